// Round 1
// baseline (642.941 us; speedup 1.0000x reference)
//
#include <hip/hip_runtime.h>
#include <cstdint>
#include <cstddef>

#define H 512
#define BATCH 8
#define SEQ 128
#define MROWS 32
#define NROWS 64

typedef __bf16 v8bf __attribute__((ext_vector_type(8)));
typedef float v4f __attribute__((ext_vector_type(4)));

__device__ __forceinline__ unsigned short f2bf(float f) {
    unsigned int u = __float_as_uint(f);
    u = (u + 0x7FFFu + ((u >> 16) & 1u)) >> 16;
    return (unsigned short)u;
}
__device__ __forceinline__ float bf2f(unsigned short h) {
    return __uint_as_float(((unsigned int)h) << 16);
}
__device__ __forceinline__ v8bf load_bf8(const unsigned short* p) {
    return *reinterpret_cast<const v8bf*>(p);
}

// ---------------------------------------------------------------------------
// prep: Wa1 (h,g) -> Wa1T bf16 (g,h)  [B^T layout for MFMA]
//       Wl  (g, 2h) fp32 -> Wlb bf16 same layout (rows already k-contiguous)
// ---------------------------------------------------------------------------
__global__ __launch_bounds__(256) void prep_kernel(
        const float* __restrict__ Wa1, const float* __restrict__ Wl,
        unsigned short* __restrict__ Wa1T, unsigned short* __restrict__ Wlb) {
    int bid = blockIdx.x;
    int t = threadIdx.x;
    if (bid < 256) {
        __shared__ float tile[32][33];
        int bx = bid & 15, by = bid >> 4;
        int lx = t & 31, ly = t >> 5;   // lx 0..31, ly 0..7
#pragma unroll
        for (int j = 0; j < 4; ++j) {
            int row = by * 32 + ly + j * 8;   // h
            int col = bx * 32 + lx;           // g
            tile[ly + j * 8][lx] = Wa1[row * H + col];
        }
        __syncthreads();
#pragma unroll
        for (int j = 0; j < 4; ++j) {
            int g = bx * 32 + ly + j * 8;
            int h = by * 32 + lx;
            Wa1T[g * H + h] = f2bf(tile[lx][ly + j * 8]);
        }
    } else {
        int i = (bid - 256) * 256 + t;   // float4 index, 131072 total
        float4 v = reinterpret_cast<const float4*>(Wl)[i];
        ushort4 o;
        o.x = f2bf(v.x); o.y = f2bf(v.y); o.z = f2bf(v.z); o.w = f2bf(v.w);
        reinterpret_cast<ushort4*>(Wlb)[i] = o;
    }
}

// ---------------------------------------------------------------------------
// attn_pool: one block per (b, s<127).  scores -> softmax -> pooled (=i_x)
// ---------------------------------------------------------------------------
__global__ __launch_bounds__(256) void attn_pool_kernel(
        const float* __restrict__ x, const unsigned short* __restrict__ Wa1T,
        const float* __restrict__ ba1, const float* __restrict__ wa2,
        float* __restrict__ ixf, unsigned short* __restrict__ ixb) {
    __shared__ __align__(16) unsigned short Xb[32][520];  // +8 pad: 2-way banks (free)
    __shared__ float attn[32];
    __shared__ float scpart[4][32];

    int bid = blockIdx.x;         // r = b*127 + s
    int b = bid / 127, s = bid % 127;
    int t = threadIdx.x;

    // stage X (32x512 fp32) -> LDS bf16
    const float4* x4 = reinterpret_cast<const float4*>(x + (size_t)(b * SEQ + s) * MROWS * H);
#pragma unroll
    for (int i = 0; i < 16; ++i) {
        int idx4 = t + i * 256;
        float4 v = x4[idx4];
        int e = idx4 * 4, m = e >> 9, h = e & 511;
        ushort4 o;
        o.x = f2bf(v.x); o.y = f2bf(v.y); o.z = f2bf(v.z); o.w = f2bf(v.w);
        *reinterpret_cast<ushort4*>(&Xb[m][h]) = o;
    }
    __syncthreads();

    int wave = t >> 6, lane = t & 63, q = lane >> 4, c16 = lane & 15;
    int mi = wave & 1, half = wave >> 1;

    const unsigned short* arow = &Xb[mi * 16 + c16][q * 8];
    float sr0 = 0.f, sr1 = 0.f, sr2 = 0.f, sr3 = 0.f;

    for (int c = half; c < 32; c += 2) {
        int g0 = c * 16;
        const unsigned short* brow = Wa1T + (size_t)(g0 + c16) * H + q * 8;
        v4f acc = {0.f, 0.f, 0.f, 0.f};
#pragma unroll
        for (int k = 0; k < 16; ++k) {
            v8bf a = load_bf8(arow + k * 32);
            v8bf bb = load_bf8(brow + k * 32);
            acc = __builtin_amdgcn_mfma_f32_16x16x32_bf16(a, bb, acc, 0, 0, 0);
        }
        float w2 = wa2[g0 + c16];
        float bav = ba1[g0 + c16];
        sr0 += w2 * tanhf(acc[0] + bav);
        sr1 += w2 * tanhf(acc[1] + bav);
        sr2 += w2 * tanhf(acc[2] + bav);
        sr3 += w2 * tanhf(acc[3] + bav);
    }
    // reduce over the 16 column-lanes (xor < 16 stays within same quad)
#pragma unroll
    for (int off = 1; off < 16; off <<= 1) {
        sr0 += __shfl_xor(sr0, off);
        sr1 += __shfl_xor(sr1, off);
        sr2 += __shfl_xor(sr2, off);
        sr3 += __shfl_xor(sr3, off);
    }
    if (c16 == 0) {
        scpart[wave][mi * 16 + q * 4 + 0] = sr0;
        scpart[wave][mi * 16 + q * 4 + 1] = sr1;
        scpart[wave][mi * 16 + q * 4 + 2] = sr2;
        scpart[wave][mi * 16 + q * 4 + 3] = sr3;
    }
    __syncthreads();

    if (t == 0) {
        float sc[32];
        float mx = -1e30f;
#pragma unroll
        for (int m = 0; m < 32; ++m) {
            float v = (m < 16) ? (scpart[0][m] + scpart[2][m])
                               : (scpart[1][m] + scpart[3][m]);
            sc[m] = v;
            mx = fmaxf(mx, v);
        }
        float sum = 0.f;
#pragma unroll
        for (int m = 0; m < 32; ++m) {
            float e = __expf(sc[m] - mx);
            attn[m] = e;
            sum += e;
        }
        float inv = 1.f / sum;
#pragma unroll
        for (int m = 0; m < 32; ++m) attn[m] *= inv;
    }
    __syncthreads();

    // pooled[h] = sum_m attn[m] * X[m][h]; 2 h per thread
    int h0 = t * 2;
    float p0 = 0.f, p1 = 0.f;
#pragma unroll
    for (int m = 0; m < 32; ++m) {
        float am = attn[m];
        p0 += am * bf2f(Xb[m][h0]);
        p1 += am * bf2f(Xb[m][h0 + 1]);
    }
    size_t r = (size_t)bid;
    ixf[r * H + h0] = p0;
    ixf[r * H + h0 + 1] = p1;
    ixb[r * H + h0] = f2bf(p0);
    ixb[r * H + h0 + 1] = f2bf(p1);
}

// ---------------------------------------------------------------------------
// ipre: i_pre[r,g] = sum_h i_x[r,h] * Wl[g, 512+h] + bl[g]   (r < 1016)
// ---------------------------------------------------------------------------
__global__ __launch_bounds__(256) void ipre_kernel(
        const unsigned short* __restrict__ ixb, const unsigned short* __restrict__ Wlb,
        const float* __restrict__ bl, float* __restrict__ ipre) {
    int bid = blockIdx.x;   // M-tile, rows bid*16..bid*16+15 (padded to 1024)
    int t = threadIdx.x;
    int wave = t >> 6, lane = t & 63, q = lane >> 4, c16 = lane & 15;
    int row16 = bid * 16;
    const unsigned short* arow = ixb + (size_t)(row16 + c16) * H + q * 8;
    for (int c = wave * 8; c < wave * 8 + 8; ++c) {
        int g0 = c * 16;
        const unsigned short* brow = Wlb + (size_t)(g0 + c16) * 1024 + 512 + q * 8;
        v4f acc = {0.f, 0.f, 0.f, 0.f};
#pragma unroll
        for (int k = 0; k < 16; ++k) {
            acc = __builtin_amdgcn_mfma_f32_16x16x32_bf16(
                load_bf8(arow + k * 32), load_bf8(brow + k * 32), acc, 0, 0, 0);
        }
        int g = g0 + c16;
        float blv = bl[g];
#pragma unroll
        for (int i = 0; i < 4; ++i) {
            int row = row16 + q * 4 + i;
            if (row < 1016) ipre[(size_t)row * H + g] = acc[i] + blv;
        }
    }
}

// ---------------------------------------------------------------------------
// main: out[b,0]=y[b,0]; s>=1: pre = y@Wy^T + i_pre, out = y + i_x*sigmoid(pre)
// ---------------------------------------------------------------------------
__global__ __launch_bounds__(256) void main_kernel(
        const float* __restrict__ y, const unsigned short* __restrict__ Wlb,
        const float* __restrict__ ixf, const float* __restrict__ ipre,
        float* __restrict__ out) {
    int s = blockIdx.x, b = blockIdx.y;
    int t = threadIdx.x;
    size_t base = (size_t)(b * SEQ + s) * NROWS * H;

    if (s == 0) {
        const float4* y4 = reinterpret_cast<const float4*>(y + base);
        float4* o4 = reinterpret_cast<float4*>(out + base);
#pragma unroll
        for (int i = 0; i < 32; ++i) o4[t + i * 256] = y4[t + i * 256];
        return;
    }

    __shared__ __align__(16) unsigned short Yb[64][520];
    __shared__ float ip_s[512];
    __shared__ float ix_s[512];

    int r = b * 127 + (s - 1);
    const float4* y4 = reinterpret_cast<const float4*>(y + base);
#pragma unroll
    for (int i = 0; i < 32; ++i) {
        int idx4 = t + i * 256;
        float4 v = y4[idx4];
        int e = idx4 * 4, n = e >> 9, h = e & 511;
        ushort4 o;
        o.x = f2bf(v.x); o.y = f2bf(v.y); o.z = f2bf(v.z); o.w = f2bf(v.w);
        *reinterpret_cast<ushort4*>(&Yb[n][h]) = o;
    }
    ip_s[t]       = ipre[(size_t)r * H + t];
    ip_s[t + 256] = ipre[(size_t)r * H + t + 256];
    ix_s[t]       = ixf[(size_t)r * H + t];
    ix_s[t + 256] = ixf[(size_t)r * H + t + 256];
    __syncthreads();

    int wave = t >> 6, lane = t & 63, q = lane >> 4, c16 = lane & 15;
    int n0 = wave * 16;
    const unsigned short* arow = &Yb[n0 + c16][q * 8];

    for (int c = 0; c < 32; ++c) {
        int g0 = c * 16;
        const unsigned short* brow = Wlb + (size_t)(g0 + c16) * 1024 + q * 8;
        v4f acc = {0.f, 0.f, 0.f, 0.f};
#pragma unroll
        for (int k = 0; k < 16; ++k) {
            acc = __builtin_amdgcn_mfma_f32_16x16x32_bf16(
                load_bf8(arow + k * 32), load_bf8(brow + k * 32), acc, 0, 0, 0);
        }
        int g = g0 + c16;
        float ip = ip_s[g];
        float ixv = ix_s[g];
#pragma unroll
        for (int i = 0; i < 4; ++i) {
            int n = n0 + q * 4 + i;
            float pre = acc[i] + ip;
            float gate = 1.f / (1.f + __expf(-pre));
            float yv = y[base + (size_t)n * H + g];
            out[base + (size_t)n * H + g] = yv + ixv * gate;
        }
    }
}

// ---------------------------------------------------------------------------
extern "C" void kernel_launch(void* const* d_in, const int* in_sizes, int n_in,
                              void* d_out, int out_size, void* d_ws, size_t ws_size,
                              hipStream_t stream) {
    const float* x   = (const float*)d_in[0];
    const float* y   = (const float*)d_in[1];
    const float* Wa1 = (const float*)d_in[2];
    const float* ba1 = (const float*)d_in[3];
    const float* wa2 = (const float*)d_in[4];
    const float* Wl  = (const float*)d_in[5];
    const float* bl  = (const float*)d_in[6];
    float* out = (float*)d_out;

    char* ws = (char*)d_ws;
    // ws layout (6.8 MB total):
    unsigned short* Wa1T = (unsigned short*)(ws);                     // 512 KB
    unsigned short* Wlb  = (unsigned short*)(ws + 524288);            // 1 MB
    float*          ixf  = (float*)(ws + 1572864);                    // 2 MB (1024 rows)
    unsigned short* ixb  = (unsigned short*)(ws + 3670016);           // 1 MB (1024 rows)
    float*          ipre = (float*)(ws + 4718592);                    // 2 MB (1024 rows)

    hipLaunchKernelGGL(prep_kernel, dim3(768), dim3(256), 0, stream, Wa1, Wl, Wa1T, Wlb);
    hipLaunchKernelGGL(attn_pool_kernel, dim3(1016), dim3(256), 0, stream,
                       x, Wa1T, ba1, wa2, ixf, ixb);
    hipLaunchKernelGGL(ipre_kernel, dim3(64), dim3(256), 0, stream, ixb, Wlb, bl, ipre);
    hipLaunchKernelGGL(main_kernel, dim3(128, 8), dim3(256), 0, stream,
                       y, Wlb, ixf, ipre, out);
}

// Round 2
// 403.489 us; speedup vs baseline: 1.5935x; 1.5935x over previous
//
#include <hip/hip_runtime.h>
#include <cstdint>
#include <cstddef>

#define H 512
#define BATCH 8
#define SEQ 128
#define MROWS 32
#define NROWS 64

typedef __bf16 v8bf __attribute__((ext_vector_type(8)));
typedef float v4f __attribute__((ext_vector_type(4)));

__device__ __forceinline__ unsigned short f2bf(float f) {
    unsigned int u = __float_as_uint(f);
    u = (u + 0x7FFFu + ((u >> 16) & 1u)) >> 16;
    return (unsigned short)u;
}
__device__ __forceinline__ float bf2f(unsigned short h) {
    return __uint_as_float(((unsigned int)h) << 16);
}
__device__ __forceinline__ v8bf load_bf8(const unsigned short* p) {
    return *reinterpret_cast<const v8bf*>(p);
}

// Swizzled B layout: frag[((c*16 + ks)*64 + lane)*8 + j] = W[g][k]
//   g = c*16 + (lane&15),  k = ks*32 + (lane>>4)*8 + j
// One wave's B-fragment load for (c,ks) = 64 lanes x 16B contiguous (1 KB).

// ---------------------------------------------------------------------------
// prep: build swizzled WyS (Wl[:, :512]), WiS (Wl[:, 512:]), WaS (Wa1^T)
// ---------------------------------------------------------------------------
__global__ __launch_bounds__(256) void prep_kernel(
        const float* __restrict__ Wa1, const float* __restrict__ Wl,
        unsigned short* __restrict__ WyS, unsigned short* __restrict__ WiS,
        unsigned short* __restrict__ WaS) {
    int tg = blockIdx.x * 256 + threadIdx.x;   // 0..98303
    int mat = tg >> 15;
    int idx = tg & 32767;
    int lane = idx & 63;
    int ks = (idx >> 6) & 15;
    int c = idx >> 10;
    int g = c * 16 + (lane & 15);
    int hb = ks * 32 + ((lane >> 4) << 3);
    unsigned short o[8];
    unsigned short* dst;
    if (mat == 0) {
        const float* s = Wl + (size_t)g * 1024 + hb;
#pragma unroll
        for (int j = 0; j < 8; ++j) o[j] = f2bf(s[j]);
        dst = WyS + (size_t)idx * 8;
    } else if (mat == 1) {
        const float* s = Wl + (size_t)g * 1024 + 512 + hb;
#pragma unroll
        for (int j = 0; j < 8; ++j) o[j] = f2bf(s[j]);
        dst = WiS + (size_t)idx * 8;
    } else {
#pragma unroll
        for (int j = 0; j < 8; ++j) o[j] = f2bf(Wa1[(size_t)(hb + j) * H + g]);
        dst = WaS + (size_t)idx * 8;
    }
    *reinterpret_cast<ushort4*>(dst)     = *reinterpret_cast<ushort4*>(&o[0]);
    *reinterpret_cast<ushort4*>(dst + 4) = *reinterpret_cast<ushort4*>(&o[4]);
}

// ---------------------------------------------------------------------------
// attn_pool: one block per (b, s<127).  scores -> softmax -> pooled (=i_x)
// ---------------------------------------------------------------------------
__global__ __launch_bounds__(256) void attn_pool_kernel(
        const float* __restrict__ x, const unsigned short* __restrict__ WaS,
        const float* __restrict__ ba1, const float* __restrict__ wa2,
        float* __restrict__ ixf, unsigned short* __restrict__ ixb) {
    __shared__ __align__(16) unsigned short Xb[32][520];
    __shared__ float attn[32];
    __shared__ float scpart[4][32];

    int bid = blockIdx.x;
    int b = bid / 127, s = bid % 127;
    int t = threadIdx.x;

    const float4* x4 = reinterpret_cast<const float4*>(x + (size_t)(b * SEQ + s) * MROWS * H);
#pragma unroll
    for (int i = 0; i < 16; ++i) {
        int idx4 = t + i * 256;
        float4 v = x4[idx4];
        int e = idx4 * 4, m = e >> 9, h = e & 511;
        ushort4 o;
        o.x = f2bf(v.x); o.y = f2bf(v.y); o.z = f2bf(v.z); o.w = f2bf(v.w);
        *reinterpret_cast<ushort4*>(&Xb[m][h]) = o;
    }
    __syncthreads();

    int wave = t >> 6, lane = t & 63, q = lane >> 4, c16 = lane & 15;
    int mi = wave & 1, half = wave >> 1;

    const unsigned short* arow = &Xb[mi * 16 + c16][q * 8];
    float sr0 = 0.f, sr1 = 0.f, sr2 = 0.f, sr3 = 0.f;

    for (int c = half; c < 32; c += 2) {
        const unsigned short* bbase = WaS + (size_t)c * 8192 + lane * 8;
        v4f acc0 = {0.f, 0.f, 0.f, 0.f};
        v4f acc1 = {0.f, 0.f, 0.f, 0.f};
#pragma unroll
        for (int ks = 0; ks < 8; ++ks) {
            acc0 = __builtin_amdgcn_mfma_f32_16x16x32_bf16(
                load_bf8(arow + (2 * ks) * 32), load_bf8(bbase + (2 * ks) * 512), acc0, 0, 0, 0);
            acc1 = __builtin_amdgcn_mfma_f32_16x16x32_bf16(
                load_bf8(arow + (2 * ks + 1) * 32), load_bf8(bbase + (2 * ks + 1) * 512), acc1, 0, 0, 0);
        }
        int g = c * 16 + c16;
        float w2 = wa2[g];
        float bav = ba1[g];
        sr0 += w2 * tanhf(acc0[0] + acc1[0] + bav);
        sr1 += w2 * tanhf(acc0[1] + acc1[1] + bav);
        sr2 += w2 * tanhf(acc0[2] + acc1[2] + bav);
        sr3 += w2 * tanhf(acc0[3] + acc1[3] + bav);
    }
#pragma unroll
    for (int off = 1; off < 16; off <<= 1) {
        sr0 += __shfl_xor(sr0, off);
        sr1 += __shfl_xor(sr1, off);
        sr2 += __shfl_xor(sr2, off);
        sr3 += __shfl_xor(sr3, off);
    }
    if (c16 == 0) {
        scpart[wave][mi * 16 + q * 4 + 0] = sr0;
        scpart[wave][mi * 16 + q * 4 + 1] = sr1;
        scpart[wave][mi * 16 + q * 4 + 2] = sr2;
        scpart[wave][mi * 16 + q * 4 + 3] = sr3;
    }
    __syncthreads();

    if (t == 0) {
        float sc[32];
        float mx = -1e30f;
#pragma unroll
        for (int m = 0; m < 32; ++m) {
            float v = (m < 16) ? (scpart[0][m] + scpart[2][m])
                               : (scpart[1][m] + scpart[3][m]);
            sc[m] = v;
            mx = fmaxf(mx, v);
        }
        float sum = 0.f;
#pragma unroll
        for (int m = 0; m < 32; ++m) {
            float e = __expf(sc[m] - mx);
            attn[m] = e;
            sum += e;
        }
        float inv = 1.f / sum;
#pragma unroll
        for (int m = 0; m < 32; ++m) attn[m] *= inv;
    }
    __syncthreads();

    int h0 = t * 2;
    float p0 = 0.f, p1 = 0.f;
#pragma unroll
    for (int m = 0; m < 32; ++m) {
        float am = attn[m];
        p0 += am * bf2f(Xb[m][h0]);
        p1 += am * bf2f(Xb[m][h0 + 1]);
    }
    size_t r = (size_t)bid;
    ixf[r * H + h0] = p0;
    ixf[r * H + h0 + 1] = p1;
    ixb[r * H + h0] = f2bf(p0);
    ixb[r * H + h0 + 1] = f2bf(p1);
}

// ---------------------------------------------------------------------------
// ipre: i_pre[r,g] = sum_h i_x[r,h] * Wi[g,h] + bl[g]   (r < 1016)
// ---------------------------------------------------------------------------
__global__ __launch_bounds__(256) void ipre_kernel(
        const unsigned short* __restrict__ ixb, const unsigned short* __restrict__ WiS,
        const float* __restrict__ bl, float* __restrict__ ipre) {
    __shared__ __align__(16) unsigned short Ax[16][520];
    int bid = blockIdx.x;
    int t = threadIdx.x;
    int row16 = bid * 16;

    const ushort4* src = reinterpret_cast<const ushort4*>(ixb + (size_t)row16 * H);
#pragma unroll
    for (int i = 0; i < 8; ++i) {
        int idx = t + i * 256;
        ushort4 v = src[idx];
        int e = idx * 4, row = e >> 9, hcol = e & 511;
        *reinterpret_cast<ushort4*>(&Ax[row][hcol]) = v;
    }
    __syncthreads();

    int wave = t >> 6, lane = t & 63, q = lane >> 4, c16 = lane & 15;
    const unsigned short* arow = &Ax[c16][q * 8];
    for (int c = wave * 8; c < wave * 8 + 8; ++c) {
        const unsigned short* bbase = WiS + (size_t)c * 8192 + lane * 8;
        v4f acc0 = {0.f, 0.f, 0.f, 0.f};
        v4f acc1 = {0.f, 0.f, 0.f, 0.f};
#pragma unroll
        for (int ks = 0; ks < 8; ++ks) {
            acc0 = __builtin_amdgcn_mfma_f32_16x16x32_bf16(
                load_bf8(arow + (2 * ks) * 32), load_bf8(bbase + (2 * ks) * 512), acc0, 0, 0, 0);
            acc1 = __builtin_amdgcn_mfma_f32_16x16x32_bf16(
                load_bf8(arow + (2 * ks + 1) * 32), load_bf8(bbase + (2 * ks + 1) * 512), acc1, 0, 0, 0);
        }
        int g = c * 16 + c16;
        float blv = bl[g];
#pragma unroll
        for (int i = 0; i < 4; ++i) {
            int row = row16 + q * 4 + i;
            if (row < 1016) ipre[(size_t)row * H + g] = acc0[i] + acc1[i] + blv;
        }
    }
}

// ---------------------------------------------------------------------------
// main: out[b,0]=y[b,0]; s>=1: pre = y@Wy^T + i_pre, out = y + i_x*sigmoid(pre)
// grid (128, 8, 2): z picks 32-row half of the 64-row tile
// ---------------------------------------------------------------------------
__global__ __launch_bounds__(256) void main_kernel(
        const float* __restrict__ y, const unsigned short* __restrict__ WyS,
        const float* __restrict__ ixf, const float* __restrict__ ipre,
        float* __restrict__ out) {
    int s = blockIdx.x, b = blockIdx.y, z = blockIdx.z;
    int t = threadIdx.x;
    size_t base = (size_t)(b * SEQ + s) * NROWS * H;

    if (s == 0) {
        const float4* y4 = reinterpret_cast<const float4*>(y + base) + z * 4096;
        float4* o4 = reinterpret_cast<float4*>(out + base) + z * 4096;
#pragma unroll
        for (int i = 0; i < 16; ++i) o4[t + i * 256] = y4[t + i * 256];
        return;
    }

    __shared__ __align__(16) unsigned short Yb[32][520];
    __shared__ float ip_s[512];
    __shared__ float ix_s[512];

    int r = b * 127 + (s - 1);
    const float4* y4 = reinterpret_cast<const float4*>(y + base + (size_t)z * 32 * H);
#pragma unroll
    for (int i = 0; i < 16; ++i) {
        int idx4 = t + i * 256;
        float4 v = y4[idx4];
        int e = idx4 * 4, n = e >> 9, h = e & 511;
        ushort4 o;
        o.x = f2bf(v.x); o.y = f2bf(v.y); o.z = f2bf(v.z); o.w = f2bf(v.w);
        *reinterpret_cast<ushort4*>(&Yb[n][h]) = o;
    }
    ip_s[t]       = ipre[(size_t)r * H + t];
    ip_s[t + 256] = ipre[(size_t)r * H + t + 256];
    ix_s[t]       = ixf[(size_t)r * H + t];
    ix_s[t + 256] = ixf[(size_t)r * H + t + 256];
    __syncthreads();

    int wave = t >> 6, lane = t & 63, q = lane >> 4, c16 = lane & 15;

    for (int c = wave * 8; c < wave * 8 + 8; ++c) {
        const unsigned short* bbase = WyS + (size_t)c * 8192 + lane * 8;
        int g = c * 16 + c16;
        float ip = ip_s[g];
        float ixv = ix_s[g];
#pragma unroll
        for (int mi = 0; mi < 2; ++mi) {
            const unsigned short* arow = &Yb[mi * 16 + c16][q * 8];
            v4f acc0 = {0.f, 0.f, 0.f, 0.f};
            v4f acc1 = {0.f, 0.f, 0.f, 0.f};
#pragma unroll
            for (int ks = 0; ks < 8; ++ks) {
                acc0 = __builtin_amdgcn_mfma_f32_16x16x32_bf16(
                    load_bf8(arow + (2 * ks) * 32), load_bf8(bbase + (2 * ks) * 512), acc0, 0, 0, 0);
                acc1 = __builtin_amdgcn_mfma_f32_16x16x32_bf16(
                    load_bf8(arow + (2 * ks + 1) * 32), load_bf8(bbase + (2 * ks + 1) * 512), acc1, 0, 0, 0);
            }
#pragma unroll
            for (int i = 0; i < 4; ++i) {
                int nl = mi * 16 + q * 4 + i;
                float pre = acc0[i] + acc1[i] + ip;
                float gate = 1.f / (1.f + __expf(-pre));
                float yv = bf2f(Yb[nl][g]);
                out[base + (size_t)(z * 32 + nl) * H + g] = yv + ixv * gate;
            }
        }
    }
}

// ---------------------------------------------------------------------------
extern "C" void kernel_launch(void* const* d_in, const int* in_sizes, int n_in,
                              void* d_out, int out_size, void* d_ws, size_t ws_size,
                              hipStream_t stream) {
    const float* x   = (const float*)d_in[0];
    const float* y   = (const float*)d_in[1];
    const float* Wa1 = (const float*)d_in[2];
    const float* ba1 = (const float*)d_in[3];
    const float* wa2 = (const float*)d_in[4];
    const float* Wl  = (const float*)d_in[5];
    const float* bl  = (const float*)d_in[6];
    float* out = (float*)d_out;

    char* ws = (char*)d_ws;
    // ws layout:
    unsigned short* WyS  = (unsigned short*)(ws);                     // 512 KB
    unsigned short* WiS  = (unsigned short*)(ws + 524288);            // 512 KB
    unsigned short* WaS  = (unsigned short*)(ws + 1048576);           // 512 KB
    float*          ixf  = (float*)(ws + 1572864);                    // 2 MB (1024 rows)
    unsigned short* ixb  = (unsigned short*)(ws + 3670016);           // 1 MB (1024 rows)
    float*          ipre = (float*)(ws + 4718592);                    // 2 MB (1024 rows)

    hipLaunchKernelGGL(prep_kernel, dim3(384), dim3(256), 0, stream, Wa1, Wl, WyS, WiS, WaS);
    hipLaunchKernelGGL(attn_pool_kernel, dim3(1016), dim3(256), 0, stream,
                       x, WaS, ba1, wa2, ixf, ixb);
    hipLaunchKernelGGL(ipre_kernel, dim3(64), dim3(256), 0, stream, ixb, WiS, bl, ipre);
    hipLaunchKernelGGL(main_kernel, dim3(128, 8, 2), dim3(256), 0, stream,
                       y, WyS, ixf, ipre, out);
}

// Round 3
// 393.597 us; speedup vs baseline: 1.6335x; 1.0251x over previous
//
#include <hip/hip_runtime.h>
#include <cstdint>
#include <cstddef>

#define H 512
#define SEQ 128

typedef __bf16 v8bf __attribute__((ext_vector_type(8)));
typedef float v4f __attribute__((ext_vector_type(4)));

__device__ __forceinline__ unsigned short f2bf(float f) {
    unsigned int u = __float_as_uint(f);
    u = (u + 0x7FFFu + ((u >> 16) & 1u)) >> 16;
    return (unsigned short)u;
}
__device__ __forceinline__ float bf2f(unsigned short h) {
    return __uint_as_float(((unsigned int)h) << 16);
}
__device__ __forceinline__ v8bf load_bf8(const unsigned short* p) {
    return *reinterpret_cast<const v8bf*>(p);
}
__device__ __forceinline__ float fast_tanh(float v) {
    float e = __expf(2.f * v);
    return 1.f - 2.f * __builtin_amdgcn_rcpf(e + 1.f);
}
__device__ __forceinline__ float fast_sigmoid(float v) {
    return __builtin_amdgcn_rcpf(1.f + __expf(-v));
}

// Swizzled B layout: frag[((c*16 + ks)*64 + lane)*8 + j] = W[g][k]
//   g = c*16 + (lane&15),  k = ks*32 + (lane>>4)*8 + j
// One wave's B-fragment load for (c,ks) = 64 lanes x 16B contiguous (1 KB).

// ---------------------------------------------------------------------------
// prep: build swizzled WyS (Wl[:, :512]), WiS (Wl[:, 512:]), WaS (Wa1^T)
// ---------------------------------------------------------------------------
__global__ __launch_bounds__(256) void prep_kernel(
        const float* __restrict__ Wa1, const float* __restrict__ Wl,
        unsigned short* __restrict__ WyS, unsigned short* __restrict__ WiS,
        unsigned short* __restrict__ WaS) {
    int tg = blockIdx.x * 256 + threadIdx.x;   // 0..98303
    int mat = tg >> 15;
    int idx = tg & 32767;
    int lane = idx & 63;
    int ks = (idx >> 6) & 15;
    int c = idx >> 10;
    int g = c * 16 + (lane & 15);
    int hb = ks * 32 + ((lane >> 4) << 3);
    unsigned short o[8];
    unsigned short* dst;
    if (mat == 0) {
        const float* s = Wl + (size_t)g * 1024 + hb;
#pragma unroll
        for (int j = 0; j < 8; ++j) o[j] = f2bf(s[j]);
        dst = WyS + (size_t)idx * 8;
    } else if (mat == 1) {
        const float* s = Wl + (size_t)g * 1024 + 512 + hb;
#pragma unroll
        for (int j = 0; j < 8; ++j) o[j] = f2bf(s[j]);
        dst = WiS + (size_t)idx * 8;
    } else {
#pragma unroll
        for (int j = 0; j < 8; ++j) o[j] = f2bf(Wa1[(size_t)(hb + j) * H + g]);
        dst = WaS + (size_t)idx * 8;
    }
    *reinterpret_cast<ushort4*>(dst)     = *reinterpret_cast<ushort4*>(&o[0]);
    *reinterpret_cast<ushort4*>(dst + 4) = *reinterpret_cast<ushort4*>(&o[4]);
}

// ---------------------------------------------------------------------------
// attn_pool: one block per (b, s<127).  wave = 32 rows x 128 cols, acc 2x8.
// ---------------------------------------------------------------------------
__global__ __launch_bounds__(256, 3) void attn_pool_kernel(
        const float* __restrict__ x, const unsigned short* __restrict__ WaS,
        const float* __restrict__ ba1, const float* __restrict__ wa2,
        float* __restrict__ ixf, unsigned short* __restrict__ ixb) {
    __shared__ __align__(16) unsigned short Xb[32][520];
    __shared__ float attn[32];
    __shared__ float scpart[4][32];

    int bid = blockIdx.x;
    int b = bid / 127, s = bid % 127;
    int t = threadIdx.x;

    const float4* x4 = reinterpret_cast<const float4*>(x + (size_t)(b * SEQ + s) * 32 * H);
#pragma unroll
    for (int i = 0; i < 16; ++i) {
        int idx4 = t + i * 256;
        float4 v = x4[idx4];
        int e = idx4 * 4, m = e >> 9, h = e & 511;
        ushort4 o;
        o.x = f2bf(v.x); o.y = f2bf(v.y); o.z = f2bf(v.z); o.w = f2bf(v.w);
        *reinterpret_cast<ushort4*>(&Xb[m][h]) = o;
    }
    __syncthreads();

    int w = t >> 6, lane = t & 63, q = lane >> 4, c16 = lane & 15;

    v4f acc[2][8];
#pragma unroll
    for (int mi = 0; mi < 2; ++mi)
#pragma unroll
        for (int ci = 0; ci < 8; ++ci) acc[mi][ci] = (v4f){0.f, 0.f, 0.f, 0.f};

    const unsigned short* Bb = WaS + (size_t)(w * 8 * 16) * 512 + lane * 8;

#pragma unroll
    for (int ks = 0; ks < 16; ++ks) {
        v8bf a0 = load_bf8(&Xb[c16][ks * 32 + q * 8]);
        v8bf a1 = load_bf8(&Xb[16 + c16][ks * 32 + q * 8]);
#pragma unroll
        for (int ci = 0; ci < 8; ++ci) {
            v8bf bb = load_bf8(Bb + (size_t)(ci * 16 + ks) * 512);
            acc[0][ci] = __builtin_amdgcn_mfma_f32_16x16x32_bf16(a0, bb, acc[0][ci], 0, 0, 0);
            acc[1][ci] = __builtin_amdgcn_mfma_f32_16x16x32_bf16(a1, bb, acc[1][ci], 0, 0, 0);
        }
    }

    float sr[2][4] = {{0.f, 0.f, 0.f, 0.f}, {0.f, 0.f, 0.f, 0.f}};
#pragma unroll
    for (int ci = 0; ci < 8; ++ci) {
        int g = (w * 8 + ci) * 16 + c16;
        float w2 = wa2[g];
        float bv = ba1[g];
#pragma unroll
        for (int mi = 0; mi < 2; ++mi)
#pragma unroll
            for (int i = 0; i < 4; ++i)
                sr[mi][i] += w2 * fast_tanh(acc[mi][ci][i] + bv);
    }
#pragma unroll
    for (int off = 1; off < 16; off <<= 1) {
#pragma unroll
        for (int mi = 0; mi < 2; ++mi)
#pragma unroll
            for (int i = 0; i < 4; ++i) sr[mi][i] += __shfl_xor(sr[mi][i], off);
    }
    if (c16 == 0) {
#pragma unroll
        for (int mi = 0; mi < 2; ++mi)
#pragma unroll
            for (int i = 0; i < 4; ++i) scpart[w][mi * 16 + q * 4 + i] = sr[mi][i];
    }
    __syncthreads();

    if (t == 0) {
        float sc[32];
        float mx = -1e30f;
#pragma unroll
        for (int m = 0; m < 32; ++m) {
            float v = scpart[0][m] + scpart[1][m] + scpart[2][m] + scpart[3][m];
            sc[m] = v;
            mx = fmaxf(mx, v);
        }
        float sum = 0.f;
#pragma unroll
        for (int m = 0; m < 32; ++m) {
            float e = __expf(sc[m] - mx);
            attn[m] = e;
            sum += e;
        }
        float inv = 1.f / sum;
#pragma unroll
        for (int m = 0; m < 32; ++m) attn[m] *= inv;
    }
    __syncthreads();

    int h0 = t * 2;
    float p0 = 0.f, p1 = 0.f;
#pragma unroll
    for (int m = 0; m < 32; ++m) {
        float am = attn[m];
        p0 += am * bf2f(Xb[m][h0]);
        p1 += am * bf2f(Xb[m][h0 + 1]);
    }
    size_t r = (size_t)bid;
    ixf[r * H + h0] = p0;
    ixf[r * H + h0 + 1] = p1;
    ixb[r * H + h0] = f2bf(p0);
    ixb[r * H + h0 + 1] = f2bf(p1);
}

// ---------------------------------------------------------------------------
// ipre: i_pre[r,g] = sum_h i_x[r,h] * Wi[g,h] + bl[g]   (r < 1016)
// grid (64, 4): block = 16 rows x 128 g; wave = 16 rows x 32 g. No LDS.
// ---------------------------------------------------------------------------
__global__ __launch_bounds__(256) void ipre_kernel(
        const unsigned short* __restrict__ ixb, const unsigned short* __restrict__ WiS,
        const float* __restrict__ bl, float* __restrict__ ipre) {
    int row16 = blockIdx.x * 16;
    int t = threadIdx.x, w = t >> 6, lane = t & 63, q = lane >> 4, c16 = lane & 15;
    int c0 = blockIdx.y * 8 + w * 2;

    v4f acc0 = {0.f, 0.f, 0.f, 0.f};
    v4f acc1 = {0.f, 0.f, 0.f, 0.f};
    const unsigned short* arow = ixb + (size_t)(row16 + c16) * H + q * 8;
#pragma unroll
    for (int ks = 0; ks < 16; ++ks) {
        v8bf a = load_bf8(arow + ks * 32);
        acc0 = __builtin_amdgcn_mfma_f32_16x16x32_bf16(
            a, load_bf8(WiS + (size_t)(c0 * 16 + ks) * 512 + lane * 8), acc0, 0, 0, 0);
        acc1 = __builtin_amdgcn_mfma_f32_16x16x32_bf16(
            a, load_bf8(WiS + (size_t)((c0 + 1) * 16 + ks) * 512 + lane * 8), acc1, 0, 0, 0);
    }
#pragma unroll
    for (int cc = 0; cc < 2; ++cc) {
        int g = (c0 + cc) * 16 + c16;
        float blv = bl[g];
        v4f a = cc ? acc1 : acc0;
#pragma unroll
        for (int i = 0; i < 4; ++i) {
            int row = row16 + q * 4 + i;
            if (row < 1016) ipre[(size_t)row * H + g] = a[i] + blv;
        }
    }
}

// ---------------------------------------------------------------------------
// main: out[b,0]=y[b,0]; s>=1: pre = y@Wy^T + i_pre, out = y + i_x*sigmoid(pre)
// block = 64 rows; wave = 64 rows x 128 cols in 2 passes of 64 cols (acc 4x4).
// ---------------------------------------------------------------------------
__global__ __launch_bounds__(256, 2) void main_kernel(
        const float* __restrict__ y, const unsigned short* __restrict__ WyS,
        const float* __restrict__ ixf, const float* __restrict__ ipre,
        float* __restrict__ out) {
    int s = blockIdx.x, b = blockIdx.y;
    int t = threadIdx.x;
    size_t base = (size_t)(b * SEQ + s) * 64 * H;

    if (s == 0) {
        const float4* y4 = reinterpret_cast<const float4*>(y + base);
        float4* o4 = reinterpret_cast<float4*>(out + base);
#pragma unroll
        for (int i = 0; i < 32; ++i) o4[t + i * 256] = y4[t + i * 256];
        return;
    }

    __shared__ __align__(16) unsigned short Yb[64][520];
    __shared__ float ip_s[512];
    __shared__ float ix_s[512];

    int r = b * 127 + (s - 1);
    const float4* y4 = reinterpret_cast<const float4*>(y + base);
#pragma unroll
    for (int i = 0; i < 32; ++i) {
        int idx4 = t + i * 256;
        float4 v = y4[idx4];
        int e = idx4 * 4, n = e >> 9, h = e & 511;
        ushort4 o;
        o.x = f2bf(v.x); o.y = f2bf(v.y); o.z = f2bf(v.z); o.w = f2bf(v.w);
        *reinterpret_cast<ushort4*>(&Yb[n][h]) = o;
    }
    ip_s[t]       = ipre[(size_t)r * H + t];
    ip_s[t + 256] = ipre[(size_t)r * H + t + 256];
    ix_s[t]       = ixf[(size_t)r * H + t];
    ix_s[t + 256] = ixf[(size_t)r * H + t + 256];
    __syncthreads();

    int w = t >> 6, lane = t & 63, q = lane >> 4, c16 = lane & 15;

#pragma unroll
    for (int pass = 0; pass < 2; ++pass) {
        v4f acc[4][4];
#pragma unroll
        for (int rt = 0; rt < 4; ++rt)
#pragma unroll
            for (int ci = 0; ci < 4; ++ci) acc[rt][ci] = (v4f){0.f, 0.f, 0.f, 0.f};

        const unsigned short* Bb = WyS + (size_t)((w * 8 + pass * 4) * 16) * 512 + lane * 8;

#pragma unroll
        for (int ks = 0; ks < 16; ++ks) {
            v8bf a[4];
#pragma unroll
            for (int rt = 0; rt < 4; ++rt)
                a[rt] = load_bf8(&Yb[rt * 16 + c16][ks * 32 + q * 8]);
#pragma unroll
            for (int ci = 0; ci < 4; ++ci) {
                v8bf bb = load_bf8(Bb + (size_t)(ci * 16 + ks) * 512);
#pragma unroll
                for (int rt = 0; rt < 4; ++rt)
                    acc[rt][ci] = __builtin_amdgcn_mfma_f32_16x16x32_bf16(
                        a[rt], bb, acc[rt][ci], 0, 0, 0);
            }
        }

#pragma unroll
        for (int ci = 0; ci < 4; ++ci) {
            int g = (w * 8 + pass * 4 + ci) * 16 + c16;
            float ip = ip_s[g];
            float ixv = ix_s[g];
#pragma unroll
            for (int rt = 0; rt < 4; ++rt)
#pragma unroll
                for (int i = 0; i < 4; ++i) {
                    int n = rt * 16 + q * 4 + i;
                    float pre = acc[rt][ci][i] + ip;
                    float gate = fast_sigmoid(pre);
                    out[base + (size_t)n * H + g] = bf2f(Yb[n][g]) + ixv * gate;
                }
        }
    }
}

// ---------------------------------------------------------------------------
extern "C" void kernel_launch(void* const* d_in, const int* in_sizes, int n_in,
                              void* d_out, int out_size, void* d_ws, size_t ws_size,
                              hipStream_t stream) {
    const float* x   = (const float*)d_in[0];
    const float* y   = (const float*)d_in[1];
    const float* Wa1 = (const float*)d_in[2];
    const float* ba1 = (const float*)d_in[3];
    const float* wa2 = (const float*)d_in[4];
    const float* Wl  = (const float*)d_in[5];
    const float* bl  = (const float*)d_in[6];
    float* out = (float*)d_out;

    char* ws = (char*)d_ws;
    unsigned short* WyS  = (unsigned short*)(ws);                     // 512 KB
    unsigned short* WiS  = (unsigned short*)(ws + 524288);            // 512 KB
    unsigned short* WaS  = (unsigned short*)(ws + 1048576);           // 512 KB
    float*          ixf  = (float*)(ws + 1572864);                    // 2 MB (1024 rows)
    unsigned short* ixb  = (unsigned short*)(ws + 3670016);           // 1 MB (1024 rows)
    float*          ipre = (float*)(ws + 4718592);                    // 2 MB (1024 rows)

    hipLaunchKernelGGL(prep_kernel, dim3(384), dim3(256), 0, stream, Wa1, Wl, WyS, WiS, WaS);
    hipLaunchKernelGGL(attn_pool_kernel, dim3(1016), dim3(256), 0, stream,
                       x, WaS, ba1, wa2, ixf, ixb);
    hipLaunchKernelGGL(ipre_kernel, dim3(64, 4), dim3(256), 0, stream, ixb, WiS, bl, ipre);
    hipLaunchKernelGGL(main_kernel, dim3(128, 8), dim3(256), 0, stream,
                       y, WyS, ixf, ipre, out);
}